// Round 1
// 456.523 us; speedup vs baseline: 1.0077x; 1.0077x over previous
//
#include <hip/hip_runtime.h>
#include <math.h>

#define D 131072      // 512*16*16
#define Q 512
#define BB 2
#define AA 16
#define CC 19
#define HW 65536      // 256*256
#define REFINE_CONF 0.968f

#define CH1 4         // chunks per queue row in k_dist2  (D/CH1 = 32768 floats)
#define RQ 4          // queue rows per block in k_dist2 (share tgt loads)
#define CH2 8         // chunks per row in k_d2           (D/CH2 = 16384 floats)

// ---------------- kernel 1: partial dist2: part[b][q][ch] ----------------
// grid (Q/RQ, CH1), 256 threads. Each block: RQ queue rows x 1 tgt chunk.
// tgt float4 loads shared across RQ rows -> tgt L2 traffic / RQ.
// Per-row accumulation order identical to the 1-row version (bit-exact).
__global__ __launch_bounds__(256) void k_dist2(const float* __restrict__ queue,
                                               const float* __restrict__ tgt,
                                               float* __restrict__ part) {
    const int qg = blockIdx.x;           // group of RQ queue rows
    const int ch = blockIdx.y;
    const int t  = threadIdx.x;
    const int q0 = qg * RQ;
    const int off4 = ch * (D / CH1 / 4);
    const float4* __restrict__ qr0 = (const float4*)(queue + (size_t)(q0 + 0) * D) + off4;
    const float4* __restrict__ qr1 = (const float4*)(queue + (size_t)(q0 + 1) * D) + off4;
    const float4* __restrict__ qr2 = (const float4*)(queue + (size_t)(q0 + 2) * D) + off4;
    const float4* __restrict__ qr3 = (const float4*)(queue + (size_t)(q0 + 3) * D) + off4;
    const float4* __restrict__ t0 = (const float4*)(tgt) + off4;
    const float4* __restrict__ t1 = (const float4*)(tgt + D) + off4;

    float a00 = 0.f, a01 = 0.f;   // row 0: batch0, batch1
    float a10 = 0.f, a11 = 0.f;
    float a20 = 0.f, a21 = 0.f;
    float a30 = 0.f, a31 = 0.f;
#pragma unroll 2
    for (int i = t; i < D / CH1 / 4; i += 256) {
        float4 u = t0[i];
        float4 v = t1[i];
        float4 qv;
        float d;
        qv = qr0[i];
        d = qv.x - u.x; a00 = fmaf(d, d, a00);
        d = qv.y - u.y; a00 = fmaf(d, d, a00);
        d = qv.z - u.z; a00 = fmaf(d, d, a00);
        d = qv.w - u.w; a00 = fmaf(d, d, a00);
        d = qv.x - v.x; a01 = fmaf(d, d, a01);
        d = qv.y - v.y; a01 = fmaf(d, d, a01);
        d = qv.z - v.z; a01 = fmaf(d, d, a01);
        d = qv.w - v.w; a01 = fmaf(d, d, a01);
        qv = qr1[i];
        d = qv.x - u.x; a10 = fmaf(d, d, a10);
        d = qv.y - u.y; a10 = fmaf(d, d, a10);
        d = qv.z - u.z; a10 = fmaf(d, d, a10);
        d = qv.w - u.w; a10 = fmaf(d, d, a10);
        d = qv.x - v.x; a11 = fmaf(d, d, a11);
        d = qv.y - v.y; a11 = fmaf(d, d, a11);
        d = qv.z - v.z; a11 = fmaf(d, d, a11);
        d = qv.w - v.w; a11 = fmaf(d, d, a11);
        qv = qr2[i];
        d = qv.x - u.x; a20 = fmaf(d, d, a20);
        d = qv.y - u.y; a20 = fmaf(d, d, a20);
        d = qv.z - u.z; a20 = fmaf(d, d, a20);
        d = qv.w - u.w; a20 = fmaf(d, d, a20);
        d = qv.x - v.x; a21 = fmaf(d, d, a21);
        d = qv.y - v.y; a21 = fmaf(d, d, a21);
        d = qv.z - v.z; a21 = fmaf(d, d, a21);
        d = qv.w - v.w; a21 = fmaf(d, d, a21);
        qv = qr3[i];
        d = qv.x - u.x; a30 = fmaf(d, d, a30);
        d = qv.y - u.y; a30 = fmaf(d, d, a30);
        d = qv.z - u.z; a30 = fmaf(d, d, a30);
        d = qv.w - u.w; a30 = fmaf(d, d, a30);
        d = qv.x - v.x; a31 = fmaf(d, d, a31);
        d = qv.y - v.y; a31 = fmaf(d, d, a31);
        d = qv.z - v.z; a31 = fmaf(d, d, a31);
        d = qv.w - v.w; a31 = fmaf(d, d, a31);
    }
    float r[8] = {a00, a01, a10, a11, a20, a21, a30, a31};
#pragma unroll
    for (int j = 0; j < 8; ++j)
        for (int o = 32; o > 0; o >>= 1) r[j] += __shfl_down(r[j], o);

    __shared__ float sred[4][8];   // [wave][acc]
    int lane = t & 63, wid = t >> 6;
    if (lane == 0) {
#pragma unroll
        for (int j = 0; j < 8; ++j) sred[wid][j] = r[j];
    }
    __syncthreads();
    if (t < 8) {
        float s = sred[0][t] + sred[1][t] + sred[2][t] + sred[3][t];
        const int rr = t >> 1;        // row within group
        const int b  = t & 1;         // batch
        part[(size_t)(b * Q + q0 + rr) * CH1 + ch] = s;
    }
}

// Device helper: fold part[] for batch b and return (minval, imin) via LDS.
// 256 threads; sv/si are caller-provided LDS (size 256 each).
__device__ __forceinline__ void fold_argmin(const float* __restrict__ part, int b, int t,
                                            float* sv, int* si) {
    const float* p0 = part + (size_t)(b * Q + t) * CH1;
    const float* p1 = part + (size_t)(b * Q + t + 256) * CH1;
    float v0 = p0[0] + p0[1] + p0[2] + p0[3];
    float v1 = p1[0] + p1[1] + p1[2] + p1[3];
    if (v1 < v0) { sv[t] = v1; si[t] = t + 256; }       // strict < => lower index on ties
    else         { sv[t] = v0; si[t] = t; }
    __syncthreads();
    for (int s = 128; s > 0; s >>= 1) {
        if (t < s) {
            float v2 = sv[t + s]; int i2 = si[t + s];
            if (v2 < sv[t] || (v2 == sv[t] && i2 < si[t])) { sv[t] = v2; si[t] = i2; }
        }
        __syncthreads();
    }
}

// ---------------- kernel 2: argmin (redundant per block) + partial d2 ----------------
// grid (BB*AA, CH2), 256 threads.
__global__ __launch_bounds__(256) void k_d2(const float* __restrict__ queue,
                                            const float* __restrict__ auged,
                                            const float* __restrict__ part,
                                            float* __restrict__ part2) {
    const int ba = blockIdx.x;           // b*16 + a
    const int ch = blockIdx.y;
    const int b  = ba >> 4;
    const int t  = threadIdx.x;
    __shared__ float sv[256];
    __shared__ int   si[256];
    fold_argmin(part, b, t, sv, si);
    const int im = si[0];

    const int off4 = ch * (D / CH2 / 4);
    const float4* __restrict__ cr = (const float4*)(queue + (size_t)im * D) + off4;
    const float4* __restrict__ ar = (const float4*)(auged + (size_t)ba * D) + off4;
    float acc = 0.f;
#pragma unroll 4
    for (int i = t; i < D / CH2 / 4; i += 256) {
        float4 c4 = cr[i];
        float4 a4 = ar[i];
        float d;
        d = a4.x - c4.x; acc = fmaf(d, d, acc);
        d = a4.y - c4.y; acc = fmaf(d, d, acc);
        d = a4.z - c4.z; acc = fmaf(d, d, acc);
        d = a4.w - c4.w; acc = fmaf(d, d, acc);
    }
    for (int o = 32; o > 0; o >>= 1) acc += __shfl_down(acc, o);
    __shared__ float s0[4];
    int lane = t & 63, wid = t >> 6;
    if (lane == 0) s0[wid] = acc;
    __syncthreads();
    if (t == 0) part2[(size_t)ba * CH2 + ch] = s0[0] + s0[1] + s0[2] + s0[3];
}

// ---------------- kernel 3: selection (redundant per block) + fused epilogue ----------------
// grid (BB*HW/256), 256 threads, 1 pixel/thread.
__global__ __launch_bounds__(256) void k_refine(const float* __restrict__ auged_logits,
                                                const float* __restrict__ tgt_logits,
                                                const int*   __restrict__ pseudo,
                                                const float* __restrict__ part,
                                                const float* __restrict__ part2,
                                                const int*   __restrict__ kptr,
                                                float* __restrict__ out_refined,
                                                float* __restrict__ out_avg) {
    const int p   = blockIdx.x * 256 + threadIdx.x;
    const int b   = p >> 16;                          // HW = 65536; whole block shares b
    const int pix = p & (HW - 1);
    const int t   = threadIdx.x;

    // ---- stage A: re-derive minval for this b (same fold/compare as k_d2) ----
    __shared__ float sv[256];
    __shared__ int   si[256];
    fold_argmin(part, b, t, sv, si);
    __shared__ float s_d2[AA];
    if (t < AA) {
        const float* pp = part2 + (size_t)(b * AA + t) * CH2;
        float s = 0.f;
#pragma unroll
        for (int c = 0; c < CH2; ++c) s += pp[c];
        s_d2[t] = s;
    }
    __syncthreads();

    // ---- stage B: thread 0 does mask + top-k selection ----
    __shared__ int   s_idx[AA];
    __shared__ int   s_kv;     // # selected finite (all have weight 1)
    __shared__ int   s_cp;     // counts > 0
    __shared__ float s_wd;     // max(sum w, 1)
    if (t == 0) {
        int k = *kptr; if (k > AA) k = AA; if (k < 0) k = 0;
        const float cd = sqrtf(sv[0]);
        float vals[AA];
        int cnt = 0;
        for (int a = 0; a < AA; ++a) {
            float dd = sqrtf(s_d2[a]);
            bool m = (dd <= cd);
            if (m) cnt++;
            vals[a] = m ? dd : INFINITY;
        }
        int kv = 0;
        for (int kk = 0; kk < k; ++kk) {
            int bi = 0; float bv = vals[0];
            for (int a = 1; a < AA; ++a)
                if (vals[a] < bv) { bv = vals[a]; bi = a; }   // strict < => first index on ties
            s_idx[kk] = bi;
            if (!isinf(bv)) kv++;
            vals[bi] = INFINITY;
        }
        s_kv = kv;
        s_wd = fmaxf((float)kv, 1.f);
        s_cp = (cnt > 0) ? 1 : 0;
    }
    __syncthreads();

    // ---- stage C: per-pixel fused softmax-avg / argmax / gate ----
    const int kv = s_kv;                               // grid-uniform
    const int pl = pseudo[p];

    // hoist tgt-logit loads so they overlap the aug loop
    const float* tb = tgt_logits + (size_t)b * CC * HW + pix;
    float tl[CC];
#pragma unroll
    for (int c = 0; c < CC; ++c) tl[c] = tb[(size_t)c * HW];

    float acc[CC];
#pragma unroll
    for (int c = 0; c < CC; ++c) acc[c] = 0.f;

    float lc[CC];
    if (kv > 0) {
        const float* base = auged_logits + ((size_t)(b * AA + s_idx[0]) * CC) * HW + pix;
#pragma unroll
        for (int c = 0; c < CC; ++c) lc[c] = base[(size_t)c * HW];
    }
    for (int kk = 0; kk < kv; ++kk) {
        float ln[CC];
        const bool more = (kk + 1 < kv);               // grid-uniform
        if (more) {
            const float* base = auged_logits + ((size_t)(b * AA + s_idx[kk + 1]) * CC) * HW + pix;
#pragma unroll
            for (int c = 0; c < CC; ++c) ln[c] = base[(size_t)c * HW];
        }
        float m = -INFINITY;
#pragma unroll
        for (int c = 0; c < CC; ++c) m = fmaxf(m, lc[c]);
        float se = 0.f;
#pragma unroll
        for (int c = 0; c < CC; ++c) { lc[c] = expf(lc[c] - m); se += lc[c]; }
        float rse = 1.f / se;
#pragma unroll
        for (int c = 0; c < CC; ++c) acc[c] = fmaf(lc[c], rse, acc[c]);
        if (more) {
#pragma unroll
            for (int c = 0; c < CC; ++c) lc[c] = ln[c];
        }
    }

    const float wd = s_wd;
    int best = 0; float bv = -INFINITY;
#pragma unroll
    for (int c = 0; c < CC; ++c) {
        float av = acc[c] / wd;
        out_avg[((size_t)(b * CC + c)) * HW + pix] = av;
        if (av > bv) { bv = av; best = c; }            // strict > => first index on ties
    }

    float tm = -INFINITY;
#pragma unroll
    for (int c = 0; c < CC; ++c) tm = fmaxf(tm, tl[c]);
    float tse = 0.f;
#pragma unroll
    for (int c = 0; c < CC; ++c) tse += expf(tl[c] - tm);
    const float pmax = 1.f / tse;

    const int label   = s_cp ? best : pl;
    const int refined = (pmax < REFINE_CONF) ? label : pl;
    out_refined[p] = (float)refined;
}

extern "C" void kernel_launch(void* const* d_in, const int* in_sizes, int n_in,
                              void* d_out, int out_size, void* d_ws, size_t ws_size,
                              hipStream_t stream) {
    const float* queue        = (const float*)d_in[0];   // [512,512,16,16]
    const float* tgt          = (const float*)d_in[1];   // [2,512,16,16]
    const float* tgt_logits   = (const float*)d_in[2];   // [2,19,256,256]
    const float* auged_feat   = (const float*)d_in[3];   // [2,16,512,16,16]
    const float* auged_logits = (const float*)d_in[4];   // [2,16,19,256,256]
    const int*   pseudo       = (const int*)d_in[5];     // [2,256,256]
    const int*   kptr         = (const int*)d_in[6];     // scalar k

    float* ws    = (float*)d_ws;
    float* part  = ws;                                   // [2*512*CH1] = 4096 floats
    float* part2 = ws + 4096;                            // [32*CH2]    = 256 floats

    float* out_refined = (float*)d_out;                  // [2*256*256]
    float* out_avg     = (float*)d_out + BB * HW;        // [2*19*256*256]

    hipLaunchKernelGGL(k_dist2, dim3(Q / RQ, CH1),   dim3(256), 0, stream, queue, tgt, part);
    hipLaunchKernelGGL(k_d2,    dim3(BB * AA, CH2),  dim3(256), 0, stream, queue, auged_feat, part, part2);
    hipLaunchKernelGGL(k_refine, dim3((BB * HW) / 256), dim3(256), 0, stream,
                       auged_logits, tgt_logits, pseudo, part, part2, kptr,
                       out_refined, out_avg);
}